// Round 12
// baseline (739.755 us; speedup 1.0000x reference)
//
#include <hip/hip_runtime.h>
#include <hip/hip_bf16.h>
#include <math.h>

#define NSPANS 16384
#define CC     16
#define DIM    300
#define DSPAN  512
#define HH     150
#define HP     160     // padded H
#define DMENT  812     // DSPAN + DIM
#define KP     320     // padded K for candidate GEMM (300 -> 320)
#define BSTR   328     // B_lds row stride in shorts

typedef short bf16x8 __attribute__((ext_vector_type(8)));
typedef float f32x4  __attribute__((ext_vector_type(4)));

__device__ __forceinline__ unsigned short f2bf(float f) {
    union { float f; unsigned int u; } v; v.f = f;
    unsigned int r = (v.u + 0x7FFFu + ((v.u >> 16) & 1u)) >> 16;   // RNE (no NaN inputs)
    return (unsigned short)r;
}

// ---------------------------------------------------------------------------
// Kernel 0 (prep): W1_bot [300x150] f32 -> Wt [160x320] bf16 transposed.
// ---------------------------------------------------------------------------
__global__ __launch_bounds__(256) void k0_prep(const float* __restrict__ W1,
                                               unsigned short* __restrict__ Wt) {
    int idx = blockIdx.x * 256 + threadIdx.x;          // 200 blocks = 51200
    int n = idx / KP, k = idx - n * KP;
    float v = (n < HH && k < DIM) ? W1[(size_t)(DSPAN + k) * HH + n] : 0.f;
    Wt[idx] = f2bf(v);
}

// ---------------------------------------------------------------------------
// Kernel 0b (prep): W1_top [512x150] f32 -> W1tT [160x512] f32 transposed
// (rows >=150 zeroed). L2-hot one-time transpose, ~5 us.
// ---------------------------------------------------------------------------
__global__ __launch_bounds__(256) void k0b_prep(const float* __restrict__ W1,
                                                float* __restrict__ W1tT) {
    int idx = blockIdx.x * 256 + threadIdx.x;          // 320 blocks = 81920
    int n = idx >> 9, k = idx & 511;
    W1tT[idx] = (n < HH) ? W1[(size_t)k * HH + n] : 0.f;
}

// ---------------------------------------------------------------------------
// Kernel 1 (v5): zero-LDS, zero-barrier. 1024 blocks x 256 thr, 16 spans.
// Thread (tc,tr) owns spans {2tr, 2tr+1} x cols {5tc..5tc+4}: streams sv
// (L1-broadcast) and 5 k-contiguous W1tT rows (L2-hot) as float4;
// 40 FMA / 7 loads per step. Per-(span,col) k-order ascending == validated
// v2 -> hs bit-identical.
// ---------------------------------------------------------------------------
__global__ __launch_bounds__(256) void k1_span(const float* __restrict__ sv,
                                               const float* __restrict__ W1tT,
                                               const float* __restrict__ b1,
                                               float* __restrict__ out) {
    const int b  = blockIdx.x;     // 1024 blocks
    const int t  = threadIdx.x;
    const int n0 = b * 16;

    // copy sv -> out: 16 rows x 128 float4 = 2048, 8 per thread
    #pragma unroll
    for (int i = 0; i < 8; ++i) {
        int idx4 = t + i * 256;
        int r = idx4 >> 7, c4 = idx4 & 127;
        float4 v = *(const float4*)(sv + (size_t)(n0 + r) * DSPAN + c4 * 4);
        *(float4*)(out + (size_t)(n0 + r) * DMENT + c4 * 4) = v;
    }

    const int tc = t & 31;          // 32 col groups x 5 cols (tc>=30 -> zero rows)
    const int tr = t >> 5;          // 8 span groups x 2 spans
    const int j0 = tc * 5;
    const int s0 = tr * 2;

    const float4* a0 = (const float4*)(sv + (size_t)(n0 + s0) * DSPAN);
    const float4* a1 = (const float4*)(sv + (size_t)(n0 + s0 + 1) * DSPAN);
    const float4* w0 = (const float4*)(W1tT + (size_t)(j0 + 0) * DSPAN);
    const float4* w1 = (const float4*)(W1tT + (size_t)(j0 + 1) * DSPAN);
    const float4* w2 = (const float4*)(W1tT + (size_t)(j0 + 2) * DSPAN);
    const float4* w3 = (const float4*)(W1tT + (size_t)(j0 + 3) * DSPAN);
    const float4* w4 = (const float4*)(W1tT + (size_t)(j0 + 4) * DSPAN);

    float acc[2][5];
    #pragma unroll
    for (int s = 0; s < 2; ++s)
        #pragma unroll
        for (int j = 0; j < 5; ++j) acc[s][j] = 0.f;

    #pragma unroll 2
    for (int kq = 0; kq < 128; ++kq) {
        float4 x0 = a0[kq];
        float4 x1 = a1[kq];
        float4 wv0 = w0[kq], wv1 = w1[kq], wv2 = w2[kq], wv3 = w3[kq], wv4 = w4[kq];
        // k ascending within float4 (x,y,z,w) and across kq -> exact v2 order
        acc[0][0] += x0.x*wv0.x; acc[0][0] += x0.y*wv0.y; acc[0][0] += x0.z*wv0.z; acc[0][0] += x0.w*wv0.w;
        acc[0][1] += x0.x*wv1.x; acc[0][1] += x0.y*wv1.y; acc[0][1] += x0.z*wv1.z; acc[0][1] += x0.w*wv1.w;
        acc[0][2] += x0.x*wv2.x; acc[0][2] += x0.y*wv2.y; acc[0][2] += x0.z*wv2.z; acc[0][2] += x0.w*wv2.w;
        acc[0][3] += x0.x*wv3.x; acc[0][3] += x0.y*wv3.y; acc[0][3] += x0.z*wv3.z; acc[0][3] += x0.w*wv3.w;
        acc[0][4] += x0.x*wv4.x; acc[0][4] += x0.y*wv4.y; acc[0][4] += x0.z*wv4.z; acc[0][4] += x0.w*wv4.w;
        acc[1][0] += x1.x*wv0.x; acc[1][0] += x1.y*wv0.y; acc[1][0] += x1.z*wv0.z; acc[1][0] += x1.w*wv0.w;
        acc[1][1] += x1.x*wv1.x; acc[1][1] += x1.y*wv1.y; acc[1][1] += x1.z*wv1.z; acc[1][1] += x1.w*wv1.w;
        acc[1][2] += x1.x*wv2.x; acc[1][2] += x1.y*wv2.y; acc[1][2] += x1.z*wv2.z; acc[1][2] += x1.w*wv2.w;
        acc[1][3] += x1.x*wv3.x; acc[1][3] += x1.y*wv3.y; acc[1][3] += x1.z*wv3.z; acc[1][3] += x1.w*wv3.w;
        acc[1][4] += x1.x*wv4.x; acc[1][4] += x1.y*wv4.y; acc[1][4] += x1.z*wv4.z; acc[1][4] += x1.w*wv4.w;
    }

    #pragma unroll
    for (int s = 0; s < 2; ++s)
        #pragma unroll
        for (int j = 0; j < 5; ++j) {
            int jj = j0 + j;
            if (jj < HH)
                out[(size_t)(n0 + s0 + s) * DMENT + DSPAN + jj] = acc[s][j] + b1[jj];
        }
}

// ---------------------------------------------------------------------------
// Kernel 2 (v4, UNCHANGED): 1024 blocks x 1024 threads (16 waves),
// wave-per-span, barrier-free K loop, 2-deep gather prefetch.
// ---------------------------------------------------------------------------
__global__ __launch_bounds__(1024) void k2_mfma(const int*   __restrict__ cand,
                                                const float* __restrict__ mask,
                                                const float* __restrict__ emb,
                                                const unsigned short* __restrict__ Wt,
                                                const float* __restrict__ W2,
                                                float*       __restrict__ out) {
    const int b  = blockIdx.x;     // 1024 blocks
    const int t  = threadIdx.x;    // 1024 threads = 16 waves
    const int n0 = b * 16;
    const int w  = t >> 6;         // wave = span within block
    const int l  = t & 63;
    const int sp = l & 15;         // A row (candidate) / B col
    const int g  = l >> 4;         // k-group

    __shared__ unsigned short B_lds[160][BSTR];   // 105 KB
    __shared__ float hsL[16][HP];
    __shared__ float w2L[HP];
    __shared__ int   candL[256];
    __shared__ float maskL[256];
    __shared__ float pL[16][16];

    if (t < 256) {
        candL[t] = cand[n0 * CC + t];
        maskL[t] = mask[n0 * CC + t];
    }
    for (int idx = t; idx < 16 * HP; idx += 1024) {
        int s = idx / HP, j = idx - s * HP;
        hsL[s][j] = (j < HH) ? out[(size_t)(n0 + s) * DMENT + DSPAN + j] : 0.f;
    }
    if (t < HP) w2L[t] = (t < HH) ? W2[t] : 0.f;
    for (int idx = t; idx < 6400; idx += 1024) {
        int row = idx / 40, seg = idx - (idx / 40) * 40;
        uint4 v = *(const uint4*)(Wt + (size_t)row * KP + seg * 8);
        *(uint4*)&B_lds[row][seg * 8] = v;
    }
    __syncthreads();

    const float* asrc = emb + (size_t)candL[w * 16 + sp] * DIM;

    float4 abuf[2][2];
    #pragma unroll
    for (int h = 0; h < 2; ++h) {
        abuf[0][h] = *(const float4*)(asrc + g * 8 + h * 4);
        abuf[1][h] = *(const float4*)(asrc + 32 + g * 8 + h * 4);
    }

    f32x4 acc[10];
    #pragma unroll
    for (int nt = 0; nt < 10; ++nt) acc[nt] = 0.f;

    #pragma unroll
    for (int kt = 0; kt < 10; ++kt) {
        const int cur = kt & 1;
        union { uint4 u; bf16x8 h8; } cv;
        cv.u.x = f2bf(abuf[cur][0].x) | ((unsigned)f2bf(abuf[cur][0].y) << 16);
        cv.u.y = f2bf(abuf[cur][0].z) | ((unsigned)f2bf(abuf[cur][0].w) << 16);
        cv.u.z = f2bf(abuf[cur][1].x) | ((unsigned)f2bf(abuf[cur][1].y) << 16);
        cv.u.w = f2bf(abuf[cur][1].z) | ((unsigned)f2bf(abuf[cur][1].w) << 16);
        bf16x8 af = cv.h8;
        if (kt + 2 < 10) {
            #pragma unroll
            for (int h = 0; h < 2; ++h) {
                int kb = (kt + 2) * 32 + g * 8 + h * 4;
                abuf[cur][h] = (kb < DIM) ? *(const float4*)(asrc + kb)
                                          : make_float4(0.f, 0.f, 0.f, 0.f);
            }
        }
        const int koff = kt * 32 + g * 8;
        #pragma unroll
        for (int nt = 0; nt < 10; ++nt) {
            bf16x8 bfr = *(const bf16x8*)&B_lds[nt * 16 + sp][koff];
            acc[nt] = __builtin_amdgcn_mfma_f32_16x16x32_bf16(af, bfr, acc[nt], 0, 0, 0);
        }
    }

    float s0 = 0.f, s1 = 0.f, s2 = 0.f, s3 = 0.f;
    #pragma unroll
    for (int nt = 0; nt < 10; ++nt) {
        int col = nt * 16 + sp;
        float hb  = hsL[w][col];
        float w2v = w2L[col];
        s0 += fmaxf(acc[nt][0] + hb, 0.f) * w2v;
        s1 += fmaxf(acc[nt][1] + hb, 0.f) * w2v;
        s2 += fmaxf(acc[nt][2] + hb, 0.f) * w2v;
        s3 += fmaxf(acc[nt][3] + hb, 0.f) * w2v;
    }
    #pragma unroll
    for (int m = 1; m < 16; m <<= 1) {
        s0 += __shfl_xor(s0, m, 64);
        s1 += __shfl_xor(s1, m, 64);
        s2 += __shfl_xor(s2, m, 64);
        s3 += __shfl_xor(s3, m, 64);
    }

    float v0 = (maskL[w * 16 + g * 4 + 0] > 0.f) ? s0 : -INFINITY;
    float v1 = (maskL[w * 16 + g * 4 + 1] > 0.f) ? s1 : -INFINITY;
    float v2 = (maskL[w * 16 + g * 4 + 2] > 0.f) ? s2 : -INFINITY;
    float v3 = (maskL[w * 16 + g * 4 + 3] > 0.f) ? s3 : -INFINITY;
    float mx = fmaxf(fmaxf(v0, v1), fmaxf(v2, v3));
    mx = fmaxf(mx, __shfl_xor(mx, 16, 64));
    mx = fmaxf(mx, __shfl_xor(mx, 32, 64));
    float e0 = expf(v0 - mx), e1 = expf(v1 - mx), e2 = expf(v2 - mx), e3 = expf(v3 - mx);
    float sm = (e0 + e1) + (e2 + e3);
    sm += __shfl_xor(sm, 16, 64);
    sm += __shfl_xor(sm, 32, 64);
    if (sp == 0) {
        pL[w][g * 4 + 0] = e0 / sm;
        pL[w][g * 4 + 1] = e1 / sm;
        pL[w][g * 4 + 2] = e2 / sm;
        pL[w][g * 4 + 3] = e3 / sm;
    }

    for (int q = l; q < 75; q += 64) {
        float4 a4 = make_float4(0.f, 0.f, 0.f, 0.f);
        #pragma unroll
        for (int c = 0; c < CC; ++c) {
            float p = pL[w][c];
            const float* rp = emb + (size_t)candL[w * 16 + c] * DIM;
            float4 v = *(const float4*)(rp + q * 4);
            a4.x += p * v.x; a4.y += p * v.y; a4.z += p * v.z; a4.w += p * v.w;
        }
        *(float4*)(out + (size_t)(n0 + w) * DMENT + DSPAN + q * 4) = a4;
    }
}

extern "C" void kernel_launch(void* const* d_in, const int* in_sizes, int n_in,
                              void* d_out, int out_size, void* d_ws, size_t ws_size,
                              hipStream_t stream) {
    const float* sv   = (const float*)d_in[0];
    const int*   cand = (const int*)d_in[1];
    const float* mask = (const float*)d_in[2];
    const float* emb  = (const float*)d_in[3];
    const float* W1   = (const float*)d_in[4];
    const float* b1   = (const float*)d_in[5];
    const float* W2   = (const float*)d_in[6];
    // b2 (d_in[7]) is softmax-invariant -> dropped
    float* out = (float*)d_out;
    unsigned short* Wt = (unsigned short*)d_ws;            // [0, 102400) bf16 Wt
    float* W1tT = (float*)((char*)d_ws + 102400);          // [102400, +327680) f32 W1_top^T

    k0_prep<<<(HP * KP) / 256, 256, 0, stream>>>(W1, Wt);
    k0b_prep<<<(HP * DSPAN) / 256, 256, 0, stream>>>(W1, W1tT);
    k1_span<<<NSPANS / 16, 256, 0, stream>>>(sv, W1tT, b1, out);
    k2_mfma<<<NSPANS / 16, 1024, 0, stream>>>(cand, mask, emb, Wt, W2, out);
}